// Round 1
// baseline (2302.176 us; speedup 1.0000x reference)
//
#include <hip/hip_runtime.h>
#include <cstddef>

// ---------------------------------------------------------------------------
// Problem constants: B=8, S=1024, D=1024, H=16, DH=64, MAX_K=4, SCALE=8.
// Outputs: d_out = [ out (B,S,D) f32 | attn (B,H,S,S) f32 ].
// ws layout (bf16): Qp | Kp | Vp  (B,H,S,DH) each 8388608 elems, ctx (B,S,D).
// ---------------------------------------------------------------------------

typedef __bf16 bf16x8 __attribute__((ext_vector_type(8)));
typedef __bf16 bf16x4 __attribute__((ext_vector_type(4)));
typedef float  floatx4 __attribute__((ext_vector_type(4)));

// -------------------- bf16 MFMA GEMM:  C[m,n] = sum_k A[m,k]*W[n,k] + b[n] --
// M=8192, N=1024, K=1024.  Block tile 128x128, BK=32, 4 waves (2x2 of 64x64).
// mfma_f32_16x16x32_bf16 layouts (verified per guide):
//   A-frag: A[m=lane&15][k=(lane>>4)*8+j]   (8 contiguous k)
//   B-frag: B[k=(lane>>4)*8+j][n=lane&15] = W[n=lane&15][k]  (8 contiguous k)
//   C/D  : col=lane&15, row=(lane>>4)*4+reg
// EPI==0: write bf16 to (B,H,S,DH) permuted (QKV proj). EPI==1: f32 row-major.

__device__ inline bf16x4 ld_cvt4(const float* p) {
    float4 f = *(const float4*)p;
    bf16x4 v = {(__bf16)f.x, (__bf16)f.y, (__bf16)f.z, (__bf16)f.w};
    return v;
}
__device__ inline bf16x4 ld_cvt4(const __bf16* p) {
    return *(const bf16x4*)p;
}

template<int EPI, typename TA>
__global__ __launch_bounds__(256) void gemm_bt(const TA* __restrict__ A,
                                               const float* __restrict__ W,
                                               const float* __restrict__ bias,
                                               void* __restrict__ outv) {
    constexpr int K = 1024;
    __shared__ __bf16 As[128 * 40];   // rows padded 32->40 to spread banks
    __shared__ __bf16 Bs[128 * 40];

    const int tid  = threadIdx.x;
    const int lane = tid & 63;
    const int wave = tid >> 6;
    const int r = lane & 15;          // fragment row/col id
    const int t = lane >> 4;          // quad id
    const int wm = (wave >> 1) * 64;  // wave sub-tile origin (m)
    const int wn = (wave & 1) * 64;   // wave sub-tile origin (n)
    const int m0 = blockIdx.y * 128;
    const int n0 = blockIdx.x * 128;

    const int rrow = tid >> 3;        // 0..31 (staging row group)
    const int rcol = (tid & 7) * 4;   // 0..28 (staging col)

    floatx4 acc[4][4] = {};

    for (int k0 = 0; k0 < K; k0 += 32) {
        __syncthreads();
        // stage A-tile (128x32) and W-tile (128x32), converting to bf16
        #pragma unroll
        for (int i = 0; i < 4; i++) {
            int row = rrow + 32 * i;
            bf16x4 av = ld_cvt4(A + (size_t)(m0 + row) * K + k0 + rcol);
            *(bf16x4*)&As[row * 40 + rcol] = av;
            bf16x4 wv = ld_cvt4(W + (size_t)(n0 + row) * K + k0 + rcol);
            *(bf16x4*)&Bs[row * 40 + rcol] = wv;
        }
        __syncthreads();

        bf16x8 aF[4], bF[4];
        #pragma unroll
        for (int mi = 0; mi < 4; mi++)
            aF[mi] = *(const bf16x8*)&As[(wm + mi * 16 + r) * 40 + t * 8];
        #pragma unroll
        for (int ni = 0; ni < 4; ni++)
            bF[ni] = *(const bf16x8*)&Bs[(wn + ni * 16 + r) * 40 + t * 8];

        #pragma unroll
        for (int mi = 0; mi < 4; mi++)
            #pragma unroll
            for (int ni = 0; ni < 4; ni++)
                acc[mi][ni] = __builtin_amdgcn_mfma_f32_16x16x32_bf16(
                    aF[mi], bF[ni], acc[mi][ni], 0, 0, 0);
    }

    // epilogue
    #pragma unroll
    for (int mi = 0; mi < 4; mi++) {
        #pragma unroll
        for (int ni = 0; ni < 4; ni++) {
            #pragma unroll
            for (int j = 0; j < 4; j++) {
                int rg = m0 + wm + mi * 16 + t * 4 + j;   // m index (b*S+s)
                int cg = n0 + wn + ni * 16 + r;           // n index (h*DH+dh)
                float v = acc[mi][ni][j] + bias[cg];
                if constexpr (EPI == 0) {
                    __bf16* o = (__bf16*)outv;
                    int bb = rg >> 10, s = rg & 1023;
                    int hh = cg >> 6,  dh = cg & 63;
                    o[((size_t)(bb * 16 + hh) * 1024 + s) * 64 + dh] = (__bf16)v;
                } else {
                    float* o = (float*)outv;
                    o[(size_t)rg * 1024 + cg] = v;
                }
            }
        }
    }
}

// -------------------- fused attention (fp32 VALU baseline) -----------------
// Block: 8 q-rows of one (b,h). 256 thr: qi=tid>>5 (q row), c=tid&31.
// Phases: QK^T(+rel-k, mask) -> softmax (+bucket sums for rel-v)
//         -> write normalized attn -> AV -> epilogue(+rel-v) -> ctx bf16.

__device__ inline void stage64(const __bf16* __restrict__ src,
                               float (*dst)[68], int tid) {
    // 64 rows x 64 cols bf16 -> LDS fp32 [64][68]
    int row = tid >> 2;
    int col = (tid & 3) * 16;
    union { uint4 u; __bf16 e[8]; } x0, x1;
    x0.u = *(const uint4*)(src + row * 64 + col);
    x1.u = *(const uint4*)(src + row * 64 + col + 8);
    #pragma unroll
    for (int j = 0; j < 8; j++) {
        dst[row][col + j]     = (float)x0.e[j];
        dst[row][col + 8 + j] = (float)x1.e[j];
    }
}

__global__ __launch_bounds__(256) void attn_fused(
    const __bf16* __restrict__ Qp, const __bf16* __restrict__ Kp,
    const __bf16* __restrict__ Vp, const int* __restrict__ mask,
    const float* __restrict__ pe_k, const float* __restrict__ pe_v,
    float* __restrict__ attn_out, __bf16* __restrict__ ctx) {

    const int b = blockIdx.z, h = blockIdx.y;
    const int q0 = blockIdx.x * 8;
    const int tid = threadIdx.x;
    const int qi = tid >> 5;          // 0..7
    const int c  = tid & 31;          // 0..31
    const int qg = q0 + qi;

    __shared__ float sc[8][1024];     // scores / unnormalized exp  (32 KB)
    __shared__ float kv[64][68];      // K/V tile staging (17.4 KB)
    __shared__ float pek[9][64];
    __shared__ float pev[9][64];
    __shared__ float rk[8][9];        // rel-k scores (pre /SCALE)
    __shared__ float wb[8][9];        // rel-v bucket sums (unnormalized)

    for (int i = tid; i < 9 * 64; i += 256) {
        (&pek[0][0])[i] = pe_k[i];
        (&pev[0][0])[i] = pe_v[i];
    }

    // q row into registers (fp32 from bf16)
    float qreg[64];
    {
        const __bf16* qptr = Qp + ((size_t)(b * 16 + h) * 1024 + qg) * 64;
        const uint4* qp4 = (const uint4*)qptr;
        #pragma unroll
        for (int i = 0; i < 8; i++) {
            union { uint4 u; __bf16 e[8]; } x;
            x.u = qp4[i];
            #pragma unroll
            for (int j = 0; j < 8; j++) qreg[i * 8 + j] = (float)x.e[j];
        }
    }
    __syncthreads();  // pek/pev ready

    // rel-k: 9 dots per q row (lanes c<9 of each row group)
    if (c < 9) {
        float a = 0.f;
        #pragma unroll
        for (int d = 0; d < 64; d++) a += qreg[d] * pek[c][d];
        rk[qi][c] = a * 0.125f;       // pre-divided by SCALE
    }
    // (rk written/read within the same half-wave; no barrier needed)

    // ---------------- QK^T ----------------
    const __bf16* khead = Kp + (size_t)(b * 16 + h) * 1024 * 64;
    for (int kt = 0; kt < 16; kt++) {
        __syncthreads();
        stage64(khead + (size_t)kt * 64 * 64, kv, tid);
        __syncthreads();

        float a0 = 0.f, a1 = 0.f;
        #pragma unroll
        for (int d = 0; d < 64; d += 4) {
            float4 v0 = *(const float4*)&kv[c][d];
            float4 v1 = *(const float4*)&kv[c + 32][d];
            a0 += qreg[d] * v0.x + qreg[d + 1] * v0.y
                + qreg[d + 2] * v0.z + qreg[d + 3] * v0.w;
            a1 += qreg[d] * v1.x + qreg[d + 1] * v1.y
                + qreg[d + 2] * v1.z + qreg[d + 3] * v1.w;
        }
        int k0g = kt * 64 + c, k1g = k0g + 32;
        int d0 = min(max(k0g - qg, -4), 4) + 4;
        int d1 = min(max(k1g - qg, -4), 4) + 4;
        float s0 = a0 * 0.125f + rk[qi][d0];
        float s1 = a1 * 0.125f + rk[qi][d1];
        if (mask[b * 1024 + k0g] == 0) s0 = -1e30f;
        if (mask[b * 1024 + k1g] == 0) s1 = -1e30f;
        sc[qi][k0g] = s0;
        sc[qi][k1g] = s1;
    }

    // ---------------- softmax (per row group = 32 lanes of one wave) -------
    float mx = -1e30f;
    #pragma unroll
    for (int i = 0; i < 32; i++) mx = fmaxf(mx, sc[qi][c + 32 * i]);
    #pragma unroll
    for (int off = 16; off >= 1; off >>= 1) mx = fmaxf(mx, __shfl_xor(mx, off));

    float ssum = 0.f, slo = 0.f, shi = 0.f;
    #pragma unroll
    for (int i = 0; i < 32; i++) {
        int k = c + 32 * i;
        float e = __expf(sc[qi][k] - mx);
        sc[qi][k] = e;
        ssum += e;
        if (k <= qg - 4) slo += e;
        else if (k >= qg + 4) shi += e;
    }
    #pragma unroll
    for (int off = 16; off >= 1; off >>= 1) {
        ssum += __shfl_xor(ssum, off);
        slo  += __shfl_xor(slo, off);
        shi  += __shfl_xor(shi, off);
    }
    float inv = 1.f / ssum;

    if (c == 0) { wb[qi][0] = slo; wb[qi][8] = shi; }
    if (c >= 1 && c <= 7) {
        int k = qg + (c - 4);
        wb[qi][c] = (k >= 0 && k < 1024) ? sc[qi][k] : 0.f;
    }

    // write normalized attention to global
    {
        float* arow = attn_out + ((size_t)(b * 16 + h) * 1024 + qg) * 1024;
        #pragma unroll
        for (int i = 0; i < 32; i++) {
            int k = c + 32 * i;
            arow[k] = sc[qi][k] * inv;
        }
    }

    // ---------------- AV ----------------
    // thread (qi, c): d-octet cd=c&7 (8 cols), k-subset ck=c>>3 (16 k/tile)
    const int cd = c & 7, ck = c >> 3;
    float oa[8] = {0, 0, 0, 0, 0, 0, 0, 0};
    const __bf16* vhead = Vp + (size_t)(b * 16 + h) * 1024 * 64;
    for (int vt = 0; vt < 16; vt++) {
        __syncthreads();
        stage64(vhead + (size_t)vt * 64 * 64, kv, tid);
        __syncthreads();
        #pragma unroll
        for (int u = 0; u < 16; u++) {
            int kl = ck + 4 * u;
            float e = sc[qi][vt * 64 + kl];
            float4 v0 = *(const float4*)&kv[kl][cd * 8];
            float4 v1 = *(const float4*)&kv[kl][cd * 8 + 4];
            oa[0] += e * v0.x; oa[1] += e * v0.y;
            oa[2] += e * v0.z; oa[3] += e * v0.w;
            oa[4] += e * v1.x; oa[5] += e * v1.y;
            oa[6] += e * v1.z; oa[7] += e * v1.w;
        }
    }
    // reduce across the 4 k-subsets (lane bits 3,4 within the wave)
    #pragma unroll
    for (int i = 0; i < 8; i++) {
        oa[i] += __shfl_xor(oa[i], 8);
        oa[i] += __shfl_xor(oa[i], 16);
    }

    if (ck == 0) {
        union { uint4 u; __bf16 e[8]; } o;
        #pragma unroll
        for (int i = 0; i < 8; i++) {
            int d = cd * 8 + i;
            float val = oa[i];
            #pragma unroll
            for (int j = 0; j < 9; j++) val += wb[qi][j] * pev[j][d];
            o.e[i] = (__bf16)(val * inv);
        }
        *(uint4*)(ctx + ((size_t)(b * 1024 + qg)) * 1024 + h * 64 + cd * 8) = o.u;
    }
}

// ---------------------------------------------------------------------------
extern "C" void kernel_launch(void* const* d_in, const int* in_sizes, int n_in,
                              void* d_out, int out_size, void* d_ws, size_t ws_size,
                              hipStream_t stream) {
    const float* query = (const float*)d_in[0];
    const float* key   = (const float*)d_in[1];
    const float* value = (const float*)d_in[2];
    const int*   mask  = (const int*)d_in[3];
    const float* Wq = (const float*)d_in[4];
    const float* bq = (const float*)d_in[5];
    const float* Wk = (const float*)d_in[6];
    const float* bk = (const float*)d_in[7];
    const float* Wv = (const float*)d_in[8];
    const float* bv = (const float*)d_in[9];
    const float* Wo = (const float*)d_in[10];
    const float* bo = (const float*)d_in[11];
    const float* pe_k = (const float*)d_in[12];
    const float* pe_v = (const float*)d_in[13];

    __bf16* Qp  = (__bf16*)d_ws;          // (B,H,S,DH) bf16
    __bf16* Kp  = Qp + 8388608;
    __bf16* Vp  = Kp + 8388608;
    __bf16* ctx = Vp + 8388608;           // (B,S,D) bf16
    float* outp  = (float*)d_out;         // (B,S,D) f32
    float* attnp = outp + 8388608;        // (B,H,S,S) f32

    dim3 gg(8, 64, 1);                    // N/128 x M/128
    gemm_bt<0, float><<<gg, 256, 0, stream>>>(query, Wq, bq, Qp);
    gemm_bt<0, float><<<gg, 256, 0, stream>>>(key,   Wk, bk, Kp);
    gemm_bt<0, float><<<gg, 256, 0, stream>>>(value, Wv, bv, Vp);
    attn_fused<<<dim3(128, 16, 8), 256, 0, stream>>>(Qp, Kp, Vp, mask,
                                                     pe_k, pe_v, attnp, ctx);
    gemm_bt<1, __bf16><<<gg, 256, 0, stream>>>(ctx, Wo, bo, outp);
}